// Round 5
// baseline (427.967 us; speedup 1.0000x reference)
//
#include <hip/hip_runtime.h>

typedef __attribute__((ext_vector_type(8))) short short8v;
typedef __attribute__((ext_vector_type(4))) short short4v;
typedef __attribute__((ext_vector_type(4))) float floatx4;

#define S_    2048
#define DIM_  2048
#define NW_   6272   // wq 0..2047 | waq 2048..2079 | wak 2080..2111 | wk 2112..4159 | pad 4160..4223 | wv 4224..6271

#define ASG(p) ((__attribute__((address_space(1))) void*)(p))
#define ASL(p) ((__attribute__((address_space(3))) void*)(p))

__device__ __forceinline__ short f2bf(float f){
  union { float f; unsigned u; } c; c.f = f;
  unsigned u = c.u;
  unsigned r = (u + 0x7fffu + ((u >> 16) & 1u)) >> 16;
  return (short)r;
}
__device__ __forceinline__ float bf2f(short s){
  union { unsigned u; float f; } c; c.u = ((unsigned)(unsigned short)s) << 16;
  return c.f;
}

// ---------------- f32 -> bf16 convert (x) ----------------
__global__ __launch_bounds__(256) void cvt_k(const float* __restrict__ in,
                                             short* __restrict__ out, int n){
  int i = blockIdx.x*256 + threadIdx.x;
  int idx = i*4;
  if (idx >= n) return;
  floatx4 v = *(const floatx4*)(in + idx);
  short4v o;
  o[0]=f2bf(v[0]); o[1]=f2bf(v[1]); o[2]=f2bf(v[2]); o[3]=f2bf(v[3]);
  *(short4v*)(out + idx) = o;
}

// ---------------- all weights -> bf16, one launch ----------------
__global__ __launch_bounds__(256)
void cvt_w(const float* wq, const float* waq, const float* wak,
           const float* wk, const float* wv, const float* wo,
           short* Wcat, short* wob){
  const float* src; short* dst; int n;
  switch (blockIdx.y){
    case 0: src=wq;  dst=Wcat;                 n=4194304; break;
    case 1: src=waq; dst=Wcat+(size_t)2048*2048; n=65536; break;
    case 2: src=wak; dst=Wcat+(size_t)2080*2048; n=65536; break;
    case 3: src=wk;  dst=Wcat+(size_t)2112*2048; n=4194304; break;
    case 4: src=wv;  dst=Wcat+(size_t)4224*2048; n=4194304; break;
    case 5: src=wo;  dst=wob;                  n=4194304; break;
    default: { // zero pad rows 4160..4223
      int idx = (blockIdx.x*256 + threadIdx.x)*4;
      if (idx < 131072){
        short4v z = {0,0,0,0};
        *(short4v*)(Wcat + (size_t)4160*2048 + idx) = z;
      }
      return;
    }
  }
  int idx = (blockIdx.x*256 + threadIdx.x)*4;
  if (idx >= n) return;
  floatx4 v = *(const floatx4*)(src + idx);
  short4v o;
  o[0]=f2bf(v[0]); o[1]=f2bf(v[1]); o[2]=f2bf(v[2]); o[3]=f2bf(v[3]);
  *(short4v*)(dst + idx) = o;
}

// ------------- fused QKV GEMM: C = X @ Wcat^T, N=6272, K=2048 -------------
__global__ __launch_bounds__(256,4)
void gemm_qkv(const short* __restrict__ A, const short* __restrict__ B,
              short* __restrict__ Cout, short* __restrict__ Vt){
  __shared__ short SH[2][128][64];
  short (*As)[64] = SH[0];
  short (*Bs)[64] = SH[1];
  const int K = 2048, N = NW_;
  int tid = threadIdx.x;
  int wave = tid>>6, lane = tid&63, quad = lane>>4, l16 = lane&15;
  int l7 = l16&7;
  int m0 = blockIdx.x*128, n0 = blockIdx.y*128;
  int wm = (wave>>1)*64, wn = (wave&1)*64;
  floatx4 acc[4][4] = {};

  int lr = lane>>3;
  int sw = (lane&7) ^ lr;
  const short* Abase = A + (size_t)(m0 + wave*32 + lr)*K + sw*8;
  const short* Bbase = B + (size_t)(n0 + wave*32 + lr)*K + sw*8;

  for (int k0 = 0; k0 < K; k0 += 64){
    __syncthreads();
    #pragma unroll
    for (int i=0;i<4;i++){
      __builtin_amdgcn_global_load_lds(ASG(Abase + (size_t)(i*8)*K + k0),
                                       ASL(&As[wave*32 + i*8][0]), 16, 0, 0);
      __builtin_amdgcn_global_load_lds(ASG(Bbase + (size_t)(i*8)*K + k0),
                                       ASL(&Bs[wave*32 + i*8][0]), 16, 0, 0);
    }
    __syncthreads();
    #pragma unroll
    for (int ks=0; ks<2; ks++){
      short8v af[4], bf[4];
      #pragma unroll
      for (int i=0;i<4;i++) af[i] = *(short8v*)&As[wm + i*16 + l16][((ks*4+quad)^l7)*8];
      #pragma unroll
      for (int j=0;j<4;j++) bf[j] = *(short8v*)&Bs[wn + j*16 + l16][((ks*4+quad)^l7)*8];
      #pragma unroll
      for (int i=0;i<4;i++)
        #pragma unroll
        for (int j=0;j<4;j++)
          acc[i][j] = __builtin_amdgcn_mfma_f32_16x16x32_bf16(af[i], bf[j], acc[i][j], 0,0,0);
    }
  }

  if (n0 < 4224){
    #pragma unroll
    for (int i=0;i<4;i++)
      #pragma unroll
      for (int r=0;r<4;r++){
        int gm = m0 + wm + i*16 + quad*4 + r;
        #pragma unroll
        for (int j=0;j<4;j++){
          int gn = n0 + wn + j*16 + l16;
          Cout[(size_t)gm*N + gn] = f2bf(acc[i][j][r]);
        }
      }
  } else {
    // V tiles: transpose via LDS (reuse SH), write Vt[feat][token]
    short* T = &SH[0][0][0];
    __syncthreads();
    #pragma unroll
    for (int i=0;i<4;i++){
      int mb = wm + i*16 + quad*4;
      int mc = mb>>3, mi = mb&7;
      #pragma unroll
      for (int j=0;j<4;j++){
        int n = wn + j*16 + l16;
        short4v p;
        p[0]=f2bf(acc[i][j][0]); p[1]=f2bf(acc[i][j][1]);
        p[2]=f2bf(acc[i][j][2]); p[3]=f2bf(acc[i][j][3]);
        *(short4v*)&T[n*128 + ((mc ^ (n&7))*8) + mi] = p;
      }
    }
    __syncthreads();
    int nl = tid>>1, half = tid&1;
    #pragma unroll
    for (int c=0;c<8;c++){
      int cc = half*8 + c;
      short8v v = *(short8v*)&T[nl*128 + ((cc ^ (nl&7))*8)];
      *(short8v*)&Vt[(size_t)(n0 - 4224 + nl)*4096 + m0 + cc*8] = v;
    }
  }
}

// ------------- O GEMM (m97-style, 128x128) -------------
__global__ __launch_bounds__(256,4)
void gemm_nt_f32(const short* __restrict__ A, const short* __restrict__ B,
                 float* __restrict__ Cout, int M, int N, int K){
  __shared__ short As[128][64];
  __shared__ short Bs[128][64];
  int tid = threadIdx.x;
  int wave = tid>>6, lane = tid&63, quad = lane>>4, l16 = lane&15;
  int l7 = l16&7;
  int m0 = blockIdx.x*128, n0 = blockIdx.y*128;
  int wm = (wave>>1)*64, wn = (wave&1)*64;
  floatx4 acc[4][4] = {};

  int lr = lane>>3;
  int sw = (lane&7) ^ lr;
  const short* Abase = A + (size_t)(m0 + wave*32 + lr)*K + sw*8;
  const short* Bbase = B + (size_t)(n0 + wave*32 + lr)*K + sw*8;

  for (int k0 = 0; k0 < K; k0 += 64){
    __syncthreads();
    #pragma unroll
    for (int i=0;i<4;i++){
      __builtin_amdgcn_global_load_lds(ASG(Abase + (size_t)(i*8)*K + k0),
                                       ASL(&As[wave*32 + i*8][0]), 16, 0, 0);
      __builtin_amdgcn_global_load_lds(ASG(Bbase + (size_t)(i*8)*K + k0),
                                       ASL(&Bs[wave*32 + i*8][0]), 16, 0, 0);
    }
    __syncthreads();
    #pragma unroll
    for (int ks=0; ks<2; ks++){
      short8v af[4], bf[4];
      #pragma unroll
      for (int i=0;i<4;i++) af[i] = *(short8v*)&As[wm + i*16 + l16][((ks*4+quad)^l7)*8];
      #pragma unroll
      for (int j=0;j<4;j++) bf[j] = *(short8v*)&Bs[wn + j*16 + l16][((ks*4+quad)^l7)*8];
      #pragma unroll
      for (int i=0;i<4;i++)
        #pragma unroll
        for (int j=0;j<4;j++)
          acc[i][j] = __builtin_amdgcn_mfma_f32_16x16x32_bf16(af[i], bf[j], acc[i][j], 0,0,0);
    }
  }
  #pragma unroll
  for (int i=0;i<4;i++)
    #pragma unroll
    for (int r=0;r<4;r++){
      int gm = m0 + wm + i*16 + quad*4 + r;
      #pragma unroll
      for (int j=0;j<4;j++){
        int gn = n0 + wn + j*16 + l16;
        Cout[(size_t)gm*N + gn] = acc[i][j][r];
      }
    }
}

// ---------------- RoPE on K only (in XQKV, stride 6272, offset 2112) --------
__global__ __launch_bounds__(256) void rope_k(short* __restrict__ X,
                                              const float* __restrict__ fcos,
                                              const float* __restrict__ fsin){
  int i = blockIdx.x*256 + threadIdx.x;
  int row = i >> 10;
  int p = i & 1023;
  int s = row & (S_-1);
  int pp = p & 63;
  float c = fcos[s*64+pp], sn = fsin[s*64+pp];
  size_t a = (size_t)row*NW_ + 2112 + p*2;
  int v = *(int*)(X + a);
  float re = bf2f((short)(v & 0xffff)), im = bf2f((short)(v >> 16));
  float orr = re*c - im*sn, oi = re*sn + im*c;
  *(int*)(X + a) = ((int)(unsigned short)f2bf(oi) << 16) | (unsigned short)f2bf(orr);
}

// ---------------- gate precompute: G[b][kt][q][l16*4+j] = sigmoid(qh.kh) ----
__global__ __launch_bounds__(256)
void gate_k(const short* __restrict__ X, short* __restrict__ G){
  int kt = blockIdx.x, qt = blockIdx.y, b = blockIdx.z;
  if (kt > qt) return;
  int tid = threadIdx.x, wave = tid>>6, lane = tid&63, quad = lane>>4, l16 = lane&15;
  const float NL2E = -1.44269504f;

  short8v qh = *(const short8v*)&X[(size_t)(b*2048 + qt*64 + wave*16 + l16)*NW_ + 2048 + quad*8];
  floatx4 am[4];
  #pragma unroll
  for (int j=0;j<4;j++){
    short8v kh = *(const short8v*)&X[(size_t)(b*2048 + kt*64 + j*16 + l16)*NW_ + 2080 + quad*8];
    floatx4 z = {0.f,0.f,0.f,0.f};
    am[j] = __builtin_amdgcn_mfma_f32_16x16x32_bf16(qh, kh, z, 0,0,0);
  }
  short* Gd = G + (((size_t)(b*32 + kt)*2048) + qt*64 + wave*16 + quad*4)*64 + l16*4;
  #pragma unroll
  for (int r=0;r<4;r++){
    short4v sv;
    #pragma unroll
    for (int j=0;j<4;j++){
      float g = __builtin_amdgcn_rcpf(1.f + __builtin_amdgcn_exp2f(am[j][r]*NL2E));
      sv[j] = f2bf(g);
    }
    *(short4v*)(Gd + (size_t)r*64) = sv;
  }
}

// ---------------- Flash attention v3: BQ=128, XCD-local heads, dbuf ---------
// grid = (16 h, 8 pi, 2 b): linear id = h + 16*pi + 128*b -> XCD = h%8, so all
// blocks of head h share one XCD's L2 (K+V slice per h = 1 MB; 4 MB/XCD).
// Each wave owns 32 q rows (2 sub-tiles of 16); block covers 128 q rows.
// Paired tiles (15-pi, pi): every block runs exactly 34 strips.
__global__ __launch_bounds__(256,1)
void flash_k(const short* __restrict__ Qc, const short* __restrict__ Vt,
             const short* __restrict__ G, const float* __restrict__ fcos,
             const float* __restrict__ fsin, short* __restrict__ O){
  int h = blockIdx.x, pi = blockIdx.y, b = blockIdx.z;
  int tid = threadIdx.x, wave = tid>>6, lane = tid&63, quad = lane>>4, l16 = lane&15;
  int l7 = l16&7;

  __shared__ short Ks [2][64][128];      // 32 KB
  __shared__ short Vts[2][128][64];      // 32 KB
  __shared__ short Ps [4][2][16][72];    // 18 KB

  const float CS = 1.44269504f * 0.08838834764831845f;  // log2(e)/sqrt(128)

  auto stage = [&](int kt, int buf){
    int k0 = kt*64;
    const short* Ksrc = Qc + ((size_t)(b*2048 + k0 + wave*16))*NW_ + 2112 + h*128;
    int r4 = lane>>4, c16 = lane&15;
    #pragma unroll
    for (int j=0;j<4;j++)
      __builtin_amdgcn_global_load_lds(
        ASG(Ksrc + (size_t)(j*4 + r4)*NW_ + ((c16 ^ r4 ^ ((j&1)*4))*8)),
        ASL(&Ks[buf][wave*16 + j*4][0]), 16, 0, 0);
    const short* Vsrc = Vt + ((size_t)(h*128 + wave*32 + (lane>>3)))*4096 + b*2048 + k0
                        + (((lane&7) ^ (lane>>3))*8);
    #pragma unroll
    for (int j=0;j<4;j++)
      __builtin_amdgcn_global_load_lds(
        ASG(Vsrc + (size_t)(j*8)*4096),
        ASL(&Vts[buf][wave*32 + j*8][0]), 16, 0, 0);
  };

  for (int ph = 0; ph < 2; ph++){
    int qt = ph ? pi : 15 - pi;
    int qmin0 = qt*128 + wave*32;            // wave's lowest q row
    short8v qf[2][4];
    #pragma unroll
    for (int i=0;i<2;i++){
      int srow = qmin0 + i*16 + l16;
      size_t qrow = (size_t)(b*2048 + srow);
      #pragma unroll
      for (int ks=0;ks<4;ks++)
        qf[i][ks] = *(const short8v*)&Qc[qrow*NW_ + h*128 + ks*32 + quad*8];
      // fused RoPE on Q fragments
      #pragma unroll
      for (int ks=0;ks<4;ks++)
        #pragma unroll
        for (int jj=0;jj<4;jj++){
          float re = bf2f(qf[i][ks][2*jj]), im = bf2f(qf[i][ks][2*jj+1]);
          int p = ks*16 + quad*4 + jj;
          float c = fcos[srow*64 + p], sn = fsin[srow*64 + p];
          qf[i][ks][2*jj]   = f2bf(re*c - im*sn);
          qf[i][ks][2*jj+1] = f2bf(re*sn + im*c);
        }
    }

    floatx4 oacc[2][8] = {};
    float lp[2][4] = {{0.f,0.f,0.f,0.f},{0.f,0.f,0.f,0.f}};
    int KT = 2*qt + 2;

    __syncthreads();           // protect dbuf from previous phase's readers
    stage(0, 0);
    for (int kt=0; kt<KT; kt++){
      __syncthreads();         // tile kt staged (implicit vmcnt), prev compute done
      if (kt+1 < KT) stage(kt+1, (kt+1)&1);   // overlaps with compute below
      int bc = kt&1, k0 = kt*64;

      if (k0 > qmin0 + 15) continue;   // wave-uniform; all waves still hit barrier

      // ---- QK^T, kf amortized over both q sub-tiles ----
      floatx4 sacc[2][4] = {};
      #pragma unroll
      for (int j=0;j<4;j++)
        #pragma unroll
        for (int ks2=0;ks2<4;ks2++){
          short8v kf = *(short8v*)&Ks[bc][j*16+l16][((ks2*4+quad)^l7)*8];
          sacc[0][j] = __builtin_amdgcn_mfma_f32_16x16x32_bf16(qf[0][ks2], kf, sacc[0][j], 0,0,0);
          sacc[1][j] = __builtin_amdgcn_mfma_f32_16x16x32_bf16(qf[1][ks2], kf, sacc[1][j], 0,0,0);
        }

      // ---- mask + exp + gate + Ps ----
      bool need_mask = (k0 + 63 > qmin0);
      #pragma unroll
      for (int i=0;i<2;i++){
        const short* gb = G + (((size_t)(b*32 + kt)*2048) + qmin0 + i*16 + quad*4)*64 + l16*4;
        short4v g4[4];
        #pragma unroll
        for (int r=0;r<4;r++) g4[r] = *(const short4v*)(gb + (size_t)r*64);
        int qbase = qmin0 + i*16 + quad*4;
        #pragma unroll
        for (int j=0;j<4;j++){
          int kin = k0 + j*16 + l16;
          #pragma unroll
          for (int r=0;r<4;r++){
            bool keep = !need_mask || (kin <= qbase + r);
            float p = keep ? __builtin_amdgcn_exp2f(sacc[i][j][r]*CS) : 0.f;
            lp[i][r] += p;
            Ps[wave][i][quad*4+r][j*16+l16] = f2bf(p * bf2f(g4[r][j]));
          }
        }
      }

      // ---- P·V, vf amortized over both q sub-tiles ----
      #pragma unroll
      for (int ks2=0; ks2<2; ks2++){
        short8v pf0 = *(short8v*)&Ps[wave][0][l16][ks2*32 + quad*8];
        short8v pf1 = *(short8v*)&Ps[wave][1][l16][ks2*32 + quad*8];
        #pragma unroll
        for (int dt=0; dt<8; dt++){
          short8v vf = *(short8v*)&Vts[bc][dt*16 + l16][((ks2*4+quad)^l7)*8];
          oacc[0][dt] = __builtin_amdgcn_mfma_f32_16x16x32_bf16(pf0, vf, oacc[0][dt], 0,0,0);
          oacc[1][dt] = __builtin_amdgcn_mfma_f32_16x16x32_bf16(pf1, vf, oacc[1][dt], 0,0,0);
        }
      }
    }

    #pragma unroll
    for (int i=0;i<2;i++){
      #pragma unroll
      for (int r=0;r<4;r++)
        #pragma unroll
        for (int off=1; off<16; off<<=1)
          lp[i][r] += __shfl_xor(lp[i][r], off, 64);
      #pragma unroll
      for (int r=0;r<4;r++){
        float inv = __builtin_amdgcn_rcpf(lp[i][r]);
        size_t orow = (size_t)(b*2048 + qmin0 + i*16 + quad*4 + r);
        #pragma unroll
        for (int dt=0;dt<8;dt++)
          O[orow*2048 + h*128 + dt*16 + l16] = f2bf(oacc[i][dt][r]*inv);
      }
    }
  }
}

// ---------------- launch ----------------
extern "C" void kernel_launch(void* const* d_in, const int* in_sizes, int n_in,
                              void* d_out, int out_size, void* d_ws, size_t ws_size,
                              hipStream_t stream){
  const float* x    = (const float*)d_in[0];
  const float* fcos = (const float*)d_in[2];
  const float* fsin = (const float*)d_in[3];
  const float* wq   = (const float*)d_in[4];
  const float* wk   = (const float*)d_in[5];
  const float* wv   = (const float*)d_in[6];
  const float* wo   = (const float*)d_in[7];
  const float* waq  = (const float*)d_in[8];
  const float* wak  = (const float*)d_in[9];
  float* out = (float*)d_out;

  char* ws = (char*)d_ws;
  size_t off = 0;
  short* xb   = (short*)(ws + off); off += (size_t)4096*2048*2;   // x bf16; later G (gate)
  short* Wcat = (short*)(ws + off); off += (size_t)NW_*2048*2;    // fused weights; later O
  short* wob  = (short*)(ws + off); off += (size_t)2048*2048*2;
  short* XQKV = (short*)(ws + off); off += (size_t)4096*NW_*2;    // [Q|qh|kh|K|pad|(V unused)]
  short* Vtb  = (short*)(ws + off); off += (size_t)2048*4096*2;   // V transposed
  short* G    = xb;    // gate overlays xb (x dead after gemm_qkv)
  short* Ob   = Wcat;  // flash output overlays Wcat (dead after gemm_qkv)

  cvt_k<<<8192,256,0,stream>>>(x, xb, 8388608);
  cvt_w<<<dim3(4096,7),256,0,stream>>>(wq, waq, wak, wk, wv, wo, Wcat, wob);

  gemm_qkv<<<dim3(32,49),256,0,stream>>>(xb, Wcat, XQKV, Vtb);

  rope_k<<<16384,256,0,stream>>>(XQKV, fcos, fsin);
  gate_k<<<dim3(32,32,2),256,0,stream>>>(XQKV, G);

  flash_k<<<dim3(16,8,2),256,0,stream>>>(XQKV, Vtb, G, fcos, fsin, Ob);

  gemm_nt_f32<<<dim3(32,16),256,0,stream>>>(Ob, wob, out, 4096, 2048, 2048);
}

// Round 6
// 412.850 us; speedup vs baseline: 1.0366x; 1.0366x over previous
//
#include <hip/hip_runtime.h>

typedef __attribute__((ext_vector_type(8))) short short8v;
typedef __attribute__((ext_vector_type(4))) short short4v;
typedef __attribute__((ext_vector_type(4))) float floatx4;

#define S_    2048
#define DIM_  2048
#define NW_   6272   // wq 0..2047 | waq 2048..2079 | wak 2080..2111 | wk 2112..4159 | pad 4160..4223 | wv 4224..6271

#define ASG(p) ((__attribute__((address_space(1))) void*)(p))
#define ASL(p) ((__attribute__((address_space(3))) void*)(p))

__device__ __forceinline__ short f2bf(float f){
  union { float f; unsigned u; } c; c.f = f;
  unsigned u = c.u;
  unsigned r = (u + 0x7fffu + ((u >> 16) & 1u)) >> 16;
  return (short)r;
}
__device__ __forceinline__ float bf2f(short s){
  union { unsigned u; float f; } c; c.u = ((unsigned)(unsigned short)s) << 16;
  return c.f;
}

// ---------------- f32 -> bf16 convert (x) ----------------
__global__ __launch_bounds__(256) void cvt_k(const float* __restrict__ in,
                                             short* __restrict__ out, int n){
  int i = blockIdx.x*256 + threadIdx.x;
  int idx = i*4;
  if (idx >= n) return;
  floatx4 v = *(const floatx4*)(in + idx);
  short4v o;
  o[0]=f2bf(v[0]); o[1]=f2bf(v[1]); o[2]=f2bf(v[2]); o[3]=f2bf(v[3]);
  *(short4v*)(out + idx) = o;
}

// ---------------- all weights -> bf16, one launch ----------------
__global__ __launch_bounds__(256)
void cvt_w(const float* wq, const float* waq, const float* wak,
           const float* wk, const float* wv, const float* wo,
           short* Wcat, short* wob){
  const float* src; short* dst; int n;
  switch (blockIdx.y){
    case 0: src=wq;  dst=Wcat;                 n=4194304; break;
    case 1: src=waq; dst=Wcat+(size_t)2048*2048; n=65536; break;
    case 2: src=wak; dst=Wcat+(size_t)2080*2048; n=65536; break;
    case 3: src=wk;  dst=Wcat+(size_t)2112*2048; n=4194304; break;
    case 4: src=wv;  dst=Wcat+(size_t)4224*2048; n=4194304; break;
    case 5: src=wo;  dst=wob;                  n=4194304; break;
    default: { // zero pad rows 4160..4223
      int idx = (blockIdx.x*256 + threadIdx.x)*4;
      if (idx < 131072){
        short4v z = {0,0,0,0};
        *(short4v*)(Wcat + (size_t)4160*2048 + idx) = z;
      }
      return;
    }
  }
  int idx = (blockIdx.x*256 + threadIdx.x)*4;
  if (idx >= n) return;
  floatx4 v = *(const floatx4*)(src + idx);
  short4v o;
  o[0]=f2bf(v[0]); o[1]=f2bf(v[1]); o[2]=f2bf(v[2]); o[3]=f2bf(v[3]);
  *(short4v*)(dst + idx) = o;
}

// ------------- fused QKV GEMM: C = X @ Wcat^T, N=6272, K=2048 -------------
__global__ __launch_bounds__(256,4)
void gemm_qkv(const short* __restrict__ A, const short* __restrict__ B,
              short* __restrict__ Cout, short* __restrict__ Vt){
  __shared__ short SH[2][128][64];
  short (*As)[64] = SH[0];
  short (*Bs)[64] = SH[1];
  const int K = 2048, N = NW_;
  int tid = threadIdx.x;
  int wave = tid>>6, lane = tid&63, quad = lane>>4, l16 = lane&15;
  int l7 = l16&7;
  int m0 = blockIdx.x*128, n0 = blockIdx.y*128;
  int wm = (wave>>1)*64, wn = (wave&1)*64;
  floatx4 acc[4][4] = {};

  int lr = lane>>3;
  int sw = (lane&7) ^ lr;
  const short* Abase = A + (size_t)(m0 + wave*32 + lr)*K + sw*8;
  const short* Bbase = B + (size_t)(n0 + wave*32 + lr)*K + sw*8;

  for (int k0 = 0; k0 < K; k0 += 64){
    __syncthreads();
    #pragma unroll
    for (int i=0;i<4;i++){
      __builtin_amdgcn_global_load_lds(ASG(Abase + (size_t)(i*8)*K + k0),
                                       ASL(&As[wave*32 + i*8][0]), 16, 0, 0);
      __builtin_amdgcn_global_load_lds(ASG(Bbase + (size_t)(i*8)*K + k0),
                                       ASL(&Bs[wave*32 + i*8][0]), 16, 0, 0);
    }
    __syncthreads();
    #pragma unroll
    for (int ks=0; ks<2; ks++){
      short8v af[4], bf[4];
      #pragma unroll
      for (int i=0;i<4;i++) af[i] = *(short8v*)&As[wm + i*16 + l16][((ks*4+quad)^l7)*8];
      #pragma unroll
      for (int j=0;j<4;j++) bf[j] = *(short8v*)&Bs[wn + j*16 + l16][((ks*4+quad)^l7)*8];
      #pragma unroll
      for (int i=0;i<4;i++)
        #pragma unroll
        for (int j=0;j<4;j++)
          acc[i][j] = __builtin_amdgcn_mfma_f32_16x16x32_bf16(af[i], bf[j], acc[i][j], 0,0,0);
    }
  }

  if (n0 < 4224){
    #pragma unroll
    for (int i=0;i<4;i++)
      #pragma unroll
      for (int r=0;r<4;r++){
        int gm = m0 + wm + i*16 + quad*4 + r;
        #pragma unroll
        for (int j=0;j<4;j++){
          int gn = n0 + wn + j*16 + l16;
          Cout[(size_t)gm*N + gn] = f2bf(acc[i][j][r]);
        }
      }
  } else {
    // V tiles: transpose via LDS (reuse SH), write Vt[feat][token]
    short* T = &SH[0][0][0];
    __syncthreads();
    #pragma unroll
    for (int i=0;i<4;i++){
      int mb = wm + i*16 + quad*4;
      int mc = mb>>3, mi = mb&7;
      #pragma unroll
      for (int j=0;j<4;j++){
        int n = wn + j*16 + l16;
        short4v p;
        p[0]=f2bf(acc[i][j][0]); p[1]=f2bf(acc[i][j][1]);
        p[2]=f2bf(acc[i][j][2]); p[3]=f2bf(acc[i][j][3]);
        *(short4v*)&T[n*128 + ((mc ^ (n&7))*8) + mi] = p;
      }
    }
    __syncthreads();
    int nl = tid>>1, half = tid&1;
    #pragma unroll
    for (int c=0;c<8;c++){
      int cc = half*8 + c;
      short8v v = *(short8v*)&T[nl*128 + ((cc ^ (nl&7))*8)];
      *(short8v*)&Vt[(size_t)(n0 - 4224 + nl)*4096 + m0 + cc*8] = v;
    }
  }
}

// ------------- O GEMM (m97-style, 128x128) -------------
__global__ __launch_bounds__(256,4)
void gemm_nt_f32(const short* __restrict__ A, const short* __restrict__ B,
                 float* __restrict__ Cout, int M, int N, int K){
  __shared__ short As[128][64];
  __shared__ short Bs[128][64];
  int tid = threadIdx.x;
  int wave = tid>>6, lane = tid&63, quad = lane>>4, l16 = lane&15;
  int l7 = l16&7;
  int m0 = blockIdx.x*128, n0 = blockIdx.y*128;
  int wm = (wave>>1)*64, wn = (wave&1)*64;
  floatx4 acc[4][4] = {};

  int lr = lane>>3;
  int sw = (lane&7) ^ lr;
  const short* Abase = A + (size_t)(m0 + wave*32 + lr)*K + sw*8;
  const short* Bbase = B + (size_t)(n0 + wave*32 + lr)*K + sw*8;

  for (int k0 = 0; k0 < K; k0 += 64){
    __syncthreads();
    #pragma unroll
    for (int i=0;i<4;i++){
      __builtin_amdgcn_global_load_lds(ASG(Abase + (size_t)(i*8)*K + k0),
                                       ASL(&As[wave*32 + i*8][0]), 16, 0, 0);
      __builtin_amdgcn_global_load_lds(ASG(Bbase + (size_t)(i*8)*K + k0),
                                       ASL(&Bs[wave*32 + i*8][0]), 16, 0, 0);
    }
    __syncthreads();
    #pragma unroll
    for (int ks=0; ks<2; ks++){
      short8v af[4], bf[4];
      #pragma unroll
      for (int i=0;i<4;i++) af[i] = *(short8v*)&As[wm + i*16 + l16][((ks*4+quad)^l7)*8];
      #pragma unroll
      for (int j=0;j<4;j++) bf[j] = *(short8v*)&Bs[wn + j*16 + l16][((ks*4+quad)^l7)*8];
      #pragma unroll
      for (int i=0;i<4;i++)
        #pragma unroll
        for (int j=0;j<4;j++)
          acc[i][j] = __builtin_amdgcn_mfma_f32_16x16x32_bf16(af[i], bf[j], acc[i][j], 0,0,0);
    }
  }
  #pragma unroll
  for (int i=0;i<4;i++)
    #pragma unroll
    for (int r=0;r<4;r++){
      int gm = m0 + wm + i*16 + quad*4 + r;
      #pragma unroll
      for (int j=0;j<4;j++){
        int gn = n0 + wn + j*16 + l16;
        Cout[(size_t)gm*N + gn] = acc[i][j][r];
      }
    }
}

// ---------------- RoPE on K only (in XQKV, stride 6272, offset 2112) --------
__global__ __launch_bounds__(256) void rope_k(short* __restrict__ X,
                                              const float* __restrict__ fcos,
                                              const float* __restrict__ fsin){
  int i = blockIdx.x*256 + threadIdx.x;
  int row = i >> 10;
  int p = i & 1023;
  int s = row & (S_-1);
  int pp = p & 63;
  float c = fcos[s*64+pp], sn = fsin[s*64+pp];
  size_t a = (size_t)row*NW_ + 2112 + p*2;
  int v = *(int*)(X + a);
  float re = bf2f((short)(v & 0xffff)), im = bf2f((short)(v >> 16));
  float orr = re*c - im*sn, oi = re*sn + im*c;
  *(int*)(X + a) = ((int)(unsigned short)f2bf(oi) << 16) | (unsigned short)f2bf(orr);
}

// ---------------- gate precompute: G[b][kt][q][l16*4+j] = sigmoid(qh.kh) ----
__global__ __launch_bounds__(256)
void gate_k(const short* __restrict__ X, short* __restrict__ G){
  int kt = blockIdx.x, qt = blockIdx.y, b = blockIdx.z;
  if (kt > qt) return;
  int tid = threadIdx.x, wave = tid>>6, lane = tid&63, quad = lane>>4, l16 = lane&15;
  const float NL2E = -1.44269504f;

  short8v qh = *(const short8v*)&X[(size_t)(b*2048 + qt*64 + wave*16 + l16)*NW_ + 2048 + quad*8];
  floatx4 am[4];
  #pragma unroll
  for (int j=0;j<4;j++){
    short8v kh = *(const short8v*)&X[(size_t)(b*2048 + kt*64 + j*16 + l16)*NW_ + 2080 + quad*8];
    floatx4 z = {0.f,0.f,0.f,0.f};
    am[j] = __builtin_amdgcn_mfma_f32_16x16x32_bf16(qh, kh, z, 0,0,0);
  }
  short* Gd = G + (((size_t)(b*32 + kt)*2048) + qt*64 + wave*16 + quad*4)*64 + l16*4;
  #pragma unroll
  for (int r=0;r<4;r++){
    short4v sv;
    #pragma unroll
    for (int j=0;j<4;j++){
      float g = __builtin_amdgcn_rcpf(1.f + __builtin_amdgcn_exp2f(am[j][r]*NL2E));
      sv[j] = f2bf(g);
    }
    *(short4v*)(Gd + (size_t)r*64) = sv;
  }
}

// ---------------- Flash attention v4: BQ=64, XCD-local heads, 2 blocks/CU ---
// grid = (16 h, 16 pi, 2 b): linear id = h + 16*pi + 256*b -> XCD = h%8, so
// all blocks of head h share one XCD's L2 (K+V per XCD = 4 MB = L2 size).
// Paired q-tiles (31-pi, pi): every block runs exactly 33 strips. Single-buffer
// m97-style staging (dbuf measured neutral; keeps LDS at 41 KB -> 2 blocks/CU).
__global__ __launch_bounds__(256,2)
void flash_k(const short* __restrict__ Qc, const short* __restrict__ Vt,
             const short* __restrict__ G, const float* __restrict__ fcos,
             const float* __restrict__ fsin, short* __restrict__ O){
  int h = blockIdx.x, pi = blockIdx.y, b = blockIdx.z;
  int tid = threadIdx.x, wave = tid>>6, lane = tid&63, quad = lane>>4, l16 = lane&15;
  int l7 = l16&7;

  __shared__ short Ks [64][128];     // 16 KB
  __shared__ short Vts[128][64];     // 16 KB
  __shared__ short Ps [4][16][72];   // 9 KB

  const float CS = 1.44269504f * 0.08838834764831845f;  // log2(e)/sqrt(128)

  for (int ph = 0; ph < 2; ph++){
    int qt = ph ? pi : 31 - pi;
    int srow = qt*64 + wave*16 + l16;
    size_t qrow = (size_t)(b*2048 + srow);
    short8v qf[4];
    #pragma unroll
    for (int ks=0;ks<4;ks++)
      qf[ks] = *(const short8v*)&Qc[qrow*NW_ + h*128 + ks*32 + quad*8];
    // fused RoPE on Q fragments (pairs are lane-local)
    #pragma unroll
    for (int ks=0;ks<4;ks++)
      #pragma unroll
      for (int jj=0;jj<4;jj++){
        float re = bf2f(qf[ks][2*jj]), im = bf2f(qf[ks][2*jj+1]);
        int p = ks*16 + quad*4 + jj;
        float c = fcos[srow*64 + p], sn = fsin[srow*64 + p];
        qf[ks][2*jj]   = f2bf(re*c - im*sn);
        qf[ks][2*jj+1] = f2bf(re*sn + im*c);
      }

    floatx4 oacc[8] = {};
    float lp[4] = {0.f,0.f,0.f,0.f};

    for (int kt=0; kt<=qt; kt++){
      int k0 = kt*64;
      __syncthreads();   // previous strip's LDS readers done
      {
        const short* Ksrc = Qc + ((size_t)(b*2048 + k0 + wave*16))*NW_ + 2112 + h*128;
        int r4 = lane>>4, c16 = lane&15;
        #pragma unroll
        for (int j=0;j<4;j++)
          __builtin_amdgcn_global_load_lds(
            ASG(Ksrc + (size_t)(j*4 + r4)*NW_ + ((c16 ^ r4 ^ ((j&1)*4))*8)),
            ASL(&Ks[wave*16 + j*4][0]), 16, 0, 0);
        const short* Vsrc = Vt + ((size_t)(h*128 + wave*32 + (lane>>3)))*4096 + b*2048 + k0
                            + (((lane&7) ^ (lane>>3))*8);
        #pragma unroll
        for (int j=0;j<4;j++)
          __builtin_amdgcn_global_load_lds(
            ASG(Vsrc + (size_t)(j*8)*4096),
            ASL(&Vts[wave*32 + j*8][0]), 16, 0, 0);
      }
      __syncthreads();   // staging complete (implicit vmcnt(0) drain)

      // gate loads (coalesced 8B per lane-row, L2-hot)
      const short* gb = G + (((size_t)(b*32 + kt)*2048) + qt*64 + wave*16 + quad*4)*64 + l16*4;
      short4v g4[4];
      #pragma unroll
      for (int r=0;r<4;r++) g4[r] = *(const short4v*)(gb + (size_t)r*64);

      // ---- QK^T ----
      floatx4 sacc[4] = {};
      #pragma unroll
      for (int j=0;j<4;j++)
        #pragma unroll
        for (int ks2=0;ks2<4;ks2++){
          short8v kf = *(short8v*)&Ks[j*16+l16][((ks2*4+quad)^l7)*8];
          sacc[j] = __builtin_amdgcn_mfma_f32_16x16x32_bf16(qf[ks2], kf, sacc[j], 0,0,0);
        }

      // ---- mask + exp + gate -> Ps ----
      bool diag = (kt == qt);
      int qbase = wave*16 + quad*4;
      #pragma unroll
      for (int j=0;j<4;j++){
        int kin = j*16 + l16;
        #pragma unroll
        for (int r=0;r<4;r++){
          bool keep = !diag || (kin <= qbase + r);
          float p = keep ? __builtin_amdgcn_exp2f(sacc[j][r]*CS) : 0.f;
          lp[r] += p;
          Ps[wave][quad*4+r][j*16+l16] = f2bf(p * bf2f(g4[r][j]));
        }
      }

      // ---- P·V ----
      #pragma unroll
      for (int ks2=0; ks2<2; ks2++){
        short8v pf = *(short8v*)&Ps[wave][l16][ks2*32 + quad*8];
        #pragma unroll
        for (int dt=0; dt<8; dt++){
          short8v vf = *(short8v*)&Vts[dt*16 + l16][((ks2*4+quad)^l7)*8];
          oacc[dt] = __builtin_amdgcn_mfma_f32_16x16x32_bf16(pf, vf, oacc[dt], 0,0,0);
        }
      }
    }

    #pragma unroll
    for (int r=0;r<4;r++)
      #pragma unroll
      for (int off=1; off<16; off<<=1)
        lp[r] += __shfl_xor(lp[r], off, 64);
    #pragma unroll
    for (int r=0;r<4;r++){
      float inv = __builtin_amdgcn_rcpf(lp[r]);
      size_t orow = (size_t)(b*2048 + qt*64 + wave*16 + quad*4 + r);
      #pragma unroll
      for (int dt=0;dt<8;dt++)
        O[orow*2048 + h*128 + dt*16 + l16] = f2bf(oacc[dt][r]*inv);
    }
  }
}

// ---------------- launch ----------------
extern "C" void kernel_launch(void* const* d_in, const int* in_sizes, int n_in,
                              void* d_out, int out_size, void* d_ws, size_t ws_size,
                              hipStream_t stream){
  const float* x    = (const float*)d_in[0];
  const float* fcos = (const float*)d_in[2];
  const float* fsin = (const float*)d_in[3];
  const float* wq   = (const float*)d_in[4];
  const float* wk   = (const float*)d_in[5];
  const float* wv   = (const float*)d_in[6];
  const float* wo   = (const float*)d_in[7];
  const float* waq  = (const float*)d_in[8];
  const float* wak  = (const float*)d_in[9];
  float* out = (float*)d_out;

  char* ws = (char*)d_ws;
  size_t off = 0;
  short* xb   = (short*)(ws + off); off += (size_t)4096*2048*2;   // x bf16; later G (gate)
  short* Wcat = (short*)(ws + off); off += (size_t)NW_*2048*2;    // fused weights; later O
  short* wob  = (short*)(ws + off); off += (size_t)2048*2048*2;
  short* XQKV = (short*)(ws + off); off += (size_t)4096*NW_*2;    // [Q|qh|kh|K|pad|(V unused)]
  short* Vtb  = (short*)(ws + off); off += (size_t)2048*4096*2;   // V transposed
  short* G    = xb;    // gate overlays xb (x dead after gemm_qkv)
  short* Ob   = Wcat;  // flash output overlays Wcat (dead after gemm_qkv)

  cvt_k<<<8192,256,0,stream>>>(x, xb, 8388608);
  cvt_w<<<dim3(4096,7),256,0,stream>>>(wq, waq, wak, wk, wv, wo, Wcat, wob);

  gemm_qkv<<<dim3(32,49),256,0,stream>>>(xb, Wcat, XQKV, Vtb);

  rope_k<<<16384,256,0,stream>>>(XQKV, fcos, fsin);
  gate_k<<<dim3(32,32,2),256,0,stream>>>(XQKV, G);

  flash_k<<<dim3(16,16,2),256,0,stream>>>(XQKV, Vtb, G, fcos, fsin, Ob);

  gemm_nt_f32<<<dim3(32,16),256,0,stream>>>(Ob, wob, out, 4096, 2048, 2048);
}